// Round 10
// baseline (14611.082 us; speedup 1.0000x reference)
//
#include <hip/hip_runtime.h>
#include <math.h>

typedef double f64;
#define HDIM 64
#define NNODES 1024
#define NROWS 2048
#define RPB 32              // rows per rowgroup / kAggFin block
#define NCH 8               // j-chunks (blocks per rowgroup)
#define CHJ (NNODES/NCH)    // 128 j per chunk
#define NITER 62            // 31 steps x 2 GAT iterations

__device__ __forceinline__ f64 wredsum64(f64 v){
#pragma unroll
  for(int o=32;o>0;o>>=1) v += __shfl_xor(v,o);
  return v;
}

// two-stage score, same op-order as the absmax-0 lineage
__device__ __forceinline__ void s_twostage64(const f64* ldsrow,
    const float* __restrict__ g_tr_w, const float* __restrict__ g_tr_b,
    const float* __restrict__ g_a, int h, f64& s_src, f64& s_dst){
  f64 t = (f64)g_tr_b[h];
  for(int c=0;c<HDIM;c++) t = fma(ldsrow[c], (f64)g_tr_w[c*HDIM+h], t);
  s_src = wredsum64(t*(f64)g_a[h]);
  s_dst = wredsum64(t*(f64)g_a[HDIM+h]);
}

// initial h1 + scores (1 wave/row) + folded f64 weight transpose
__global__ void k1(const float* __restrict__ x, const float* __restrict__ fw,
                   const float* __restrict__ fb,
                   const float* __restrict__ g_in_w, const float* __restrict__ g_in_b,
                   const float* __restrict__ g_tr_w, const float* __restrict__ g_tr_b,
                   const float* __restrict__ g_a,
                   const float* __restrict__ w_ih, const float* __restrict__ w_hh,
                   f64* __restrict__ w_ihT, f64* __restrict__ w_hhT,
                   f64* __restrict__ h1, f64* __restrict__ ssrc, f64* __restrict__ sdst){
  __shared__ f64 lx[4*64];
  __shared__ f64 lt[4*64];
  int wave = threadIdx.x >> 6, h = threadIdx.x & 63;
  int kk = blockIdx.x*256 + threadIdx.x;
  if(kk < 192*HDIM){
    int row=kk>>6, c=kk&63;
    w_ihT[c*192+row]=(f64)w_ih[kk];
    w_hhT[c*192+row]=(f64)w_hh[kk];
  }
  int r = blockIdx.x*4 + wave;
  int b = r >> 10, n = r & 1023;
  const float* xp = x + ((long)(b*32 + 0)*1024 + n)*6;
  f64 xh = (f64)fb[h];
#pragma unroll
  for(int f=0;f<6;f++) xh += (f64)xp[f]*(f64)fw[f*HDIM+h];
  lx[wave*64+h] = xh;
  __syncthreads();
  f64 a = (f64)g_in_b[h];
  for(int c=0;c<HDIM;c++) a += lx[wave*64+c]*(f64)g_in_w[c*HDIM+h];
  h1[(long)r*HDIM+h] = a;
  lt[wave*64+h] = a;
  __syncthreads();
  f64 s1,s2;
  s_twostage64(lt+wave*64, g_tr_w,g_tr_b,g_a, h, s1,s2);
  if(h==0){ ssrc[r]=s1; sdst[r]=s2; }
}

// Fused Agg + last-block Fin. grid = 64 rowgroups x 8 chunks = 512 blocks x 512 thr.
// Phase A (all blocks): partial aggregation for (rowgroup, chunk) -> pacc/pws.
// Phase B (last block of each rowgroup): combine + residual + [scores | GRU+next-h1+scores | FFN].
template<int M>
__global__ __launch_bounds__(512,4) void kAggFin(
    const f64* __restrict__ h1_in, const f64* __restrict__ ss_in,
    const f64* __restrict__ sd_in,
    f64* __restrict__ h1_out, f64* __restrict__ ss_out, f64* __restrict__ sd_out,
    f64* __restrict__ pacc, f64* __restrict__ pws, unsigned* __restrict__ cnt,
    const float* __restrict__ g_tr_w, const float* __restrict__ g_tr_b,
    const float* __restrict__ g_a,
    const float* __restrict__ x, const float* __restrict__ fw, const float* __restrict__ fb,
    const f64* __restrict__ w_ihT, const f64* __restrict__ w_hhT,
    const float* __restrict__ b_ih, const float* __restrict__ b_hh,
    const float* __restrict__ g_in_w, const float* __restrict__ g_in_b,
    const float* __restrict__ ffn_w, const float* __restrict__ ffn_b,
    const float* __restrict__ ffn_ow, const float* __restrict__ ffn_ob,
    float* __restrict__ out, int step, int is_final)
{
  __shared__ __align__(16) f64 htile[64*64];  // 32 KB (Phase B: lxB/lhB)
  __shared__ __align__(16) f64 wbuf[RPB*64];  // 16 KB (Phase B: lrow)
  __shared__ f64 lds_m[RPB];
  __shared__ f64 lds_sd[RPB];
  __shared__ f64 red[8];
  __shared__ unsigned lastflag;

  const int tid = threadIdx.x, wave = tid>>6, h = tid&63;
  const int chunk = blockIdx.x & (NCH-1);
  const int rg = blockIdx.x >> 3;           // 0..63
  const int batch = rg >> 5;
  const int nloc = (rg & 31)*RPB;           // node base within batch
  const long gr0 = (long)batch*NNODES + nloc;

  // ---- Phase A: identical to R9 kAgg ----
  const f64* sb = ss_in + (long)batch*NNODES;
  f64 mx = -1e300;
  for(int j=tid;j<NNODES;j+=512) mx = fmax(mx, sb[j]);
#pragma unroll
  for(int o=32;o>0;o>>=1) mx = fmax(mx, __shfl_xor(mx,o));
  if(h==0) red[wave]=mx;
  __syncthreads();
  f64 maxS = fmax(fmax(fmax(red[0],red[1]),fmax(red[2],red[3])),
                  fmax(fmax(red[4],red[5]),fmax(red[6],red[7])));
  if(tid<RPB){
    f64 sd = sd_in[gr0+tid];
    lds_sd[tid]=sd;
    f64 v = maxS + sd;
    lds_m[tid] = (v>=0.0)? v : 0.01*v;
  }
  __syncthreads();

  f64 acc0=0.0, acc1=0.0, acc2=0.0, acc3=0.0;
  f64 wsk0=0.0, wsk1=0.0, wsk2=0.0, wsk3=0.0;

  for(int st=0; st<CHJ/64; st++){
    const int j0 = chunk*CHJ + st*64;
    const f64* src = h1_in + ((long)batch*NNODES + j0)*HDIM;
#pragma unroll
    for(int k=0;k<4;k++){
      int idx = tid + k*512;
      ((double2*)htile)[idx] = ((const double2*)src)[idx];
    }
#pragma unroll
    for(int k=0;k<4;k++){
      int idx = tid + k*512;
      int row = idx>>6, jj = idx&63;
      f64 v = sb[j0+jj] + lds_sd[row];
      v = (v>=0.0)? v : 0.01*v;
      f64 e = exp(v - lds_m[row]);
      wbuf[idx] = e;
      if(k==0) wsk0+=e; else if(k==1) wsk1+=e; else if(k==2) wsk2+=e; else wsk3+=e;
    }
    __syncthreads();
    const f64* wb = wbuf + (wave*4)*64;
#pragma unroll 4
    for(int jg=0; jg<16; jg++){
      int base = jg*4*64 + h;
      f64 h0 = htile[base], h1v = htile[base+64];
      f64 h2 = htile[base+128], h3 = htile[base+192];
      double2 wa  = *(const double2*)(wb + jg*4);
      double2 wa2 = *(const double2*)(wb + jg*4 + 2);
      double2 wbv = *(const double2*)(wb + 64 + jg*4);
      double2 wb2 = *(const double2*)(wb + 64 + jg*4 + 2);
      double2 wc  = *(const double2*)(wb + 128 + jg*4);
      double2 wc2 = *(const double2*)(wb + 128 + jg*4 + 2);
      double2 wd  = *(const double2*)(wb + 192 + jg*4);
      double2 wd2 = *(const double2*)(wb + 192 + jg*4 + 2);
      acc0 = fma(wa.x,h0,acc0);  acc0 = fma(wa.y,h1v,acc0);
      acc0 = fma(wa2.x,h2,acc0); acc0 = fma(wa2.y,h3,acc0);
      acc1 = fma(wbv.x,h0,acc1); acc1 = fma(wbv.y,h1v,acc1);
      acc1 = fma(wb2.x,h2,acc1); acc1 = fma(wb2.y,h3,acc1);
      acc2 = fma(wc.x,h0,acc2);  acc2 = fma(wc.y,h1v,acc2);
      acc2 = fma(wc2.x,h2,acc2); acc2 = fma(wc2.y,h3,acc2);
      acc3 = fma(wd.x,h0,acc3);  acc3 = fma(wd.y,h1v,acc3);
      acc3 = fma(wd2.x,h2,acc3); acc3 = fma(wd2.y,h3,acc3);
    }
    __syncthreads();
  }

  const long pbase = (long)chunk*NROWS + gr0;
  pacc[(pbase + wave*4+0)*HDIM + h] = acc0;
  pacc[(pbase + wave*4+1)*HDIM + h] = acc1;
  pacc[(pbase + wave*4+2)*HDIM + h] = acc2;
  pacc[(pbase + wave*4+3)*HDIM + h] = acc3;
  f64 w0 = wredsum64(wsk0), w1 = wredsum64(wsk1);
  f64 w2 = wredsum64(wsk2), w3 = wredsum64(wsk3);
  if(h==0){
    pws[pbase + wave     ] = w0;
    pws[pbase + wave + 8 ] = w1;
    pws[pbase + wave + 16] = w2;
    pws[pbase + wave + 24] = w3;
  }

  // ---- completion protocol: last block of rowgroup does Fin ----
  __syncthreads();                // drains all threads' stores (vmcnt0 at barrier)
  if(tid==0){
    __threadfence();              // release: L2 writeback
    unsigned old = atomicAdd(&cnt[rg], 1u);
    lastflag = (old == NCH-1);
  }
  __syncthreads();
  if(!lastflag) return;
  __threadfence();                // acquire: invalidate stale lines

  // ---- Phase B: Fin for 32 rows, 8 waves x 4 rows, wave-local ----
  f64* lrow = wbuf;               // [32*64]
  f64* lxB  = htile;              // [32*64]
  f64* lhB  = htile + 2048;       // [32*64]

#pragma unroll
  for(int q=0;q<4;q++){
    int y = wave*4+q; long gr = gr0+y;
    f64 a=0.0, w=0.0;
#pragma unroll
    for(int c=0;c<NCH;c++){
      a += pacc[((long)c*NROWS+gr)*HDIM+h];
      w += pws[(long)c*NROWS+gr];
    }
    f64 gato = a/w + h1_in[gr*HDIM+h];
    lrow[y*64+h]=gato;
    if(M==0) h1_out[gr*HDIM+h] = gato;
  }
  __syncthreads();

  if(M==0){
#pragma unroll
    for(int q=0;q<4;q++){
      int y=wave*4+q; long gr=gr0+y;
      f64 s1,s2; s_twostage64(lrow+y*64, g_tr_w,g_tr_b,g_a,h,s1,s2);
      if(h==0){ ss_out[gr]=s1; sd_out[gr]=s2; }
    }
  } else {
    const bool hasxi = (step>0);
    if(hasxi){
#pragma unroll
      for(int q=0;q<4;q++){
        int y=wave*4+q;
        const float* xp = x + ((long)(batch*32+step)*1024 + nloc+y)*6;
        f64 xi=(f64)fb[h];
#pragma unroll
        for(int f=0;f<6;f++) xi += (f64)xp[f]*(f64)fw[f*HDIM+h];
        lxB[y*64+h]=xi;
      }
    }
    __syncthreads();
#pragma unroll
    for(int q=0;q<4;q++){
      int y=wave*4+q;
      f64 gato = lrow[y*64+h];
      f64 gi0=(f64)b_ih[h], gi1=(f64)b_ih[64+h], gi2=(f64)b_ih[128+h];
      f64 gh0=(f64)b_hh[h], gh1=(f64)b_hh[64+h], gh2=(f64)b_hh[128+h];
      for(int c=0;c<HDIM;c++){
        f64 o = lrow[y*64+c];
        f64 in = hasxi ? lxB[y*64+c] : o;
        gi0 += in*w_ihT[c*192+h]; gi1 += in*w_ihT[c*192+64+h]; gi2 += in*w_ihT[c*192+128+h];
        if(hasxi){
          gh0 += o*w_hhT[c*192+h]; gh1 += o*w_hhT[c*192+64+h]; gh2 += o*w_hhT[c*192+128+h];
        }
      }
      f64 rr = 1.0/(1.0+exp(-(gi0+gh0)));
      f64 zz = 1.0/(1.0+exp(-(gi1+gh1)));
      f64 nn = tanh(gi2 + rr*gh2);
      f64 hn = hasxi ? ((1.0-zz)*nn + zz*gato) : (1.0-zz)*nn;
      lhB[y*64+h] = hn;
    }
    __syncthreads();
    if(!is_final){
#pragma unroll
      for(int q=0;q<4;q++){
        int y=wave*4+q; long gr=gr0+y;
        f64 a1 = (f64)g_in_b[h];
        for(int c=0;c<HDIM;c++) a1 += lhB[y*64+c]*(f64)g_in_w[c*HDIM+h];
        h1_out[gr*HDIM+h]=a1;
        lrow[y*64+h]=a1;
      }
      __syncthreads();
#pragma unroll
      for(int q=0;q<4;q++){
        int y=wave*4+q; long gr=gr0+y;
        f64 s1,s2; s_twostage64(lrow+y*64, g_tr_w,g_tr_b,g_a,h,s1,s2);
        if(h==0){ ss_out[gr]=s1; sd_out[gr]=s2; }
      }
    } else {
#pragma unroll
      for(int q=0;q<4;q++){
        int y=wave*4+q; long gr=gr0+y;
        f64 hid = (f64)ffn_b[h];
        for(int c=0;c<HDIM;c++) hid += lhB[y*64+c]*(f64)ffn_w[c*HDIM+h];
        hid = (hid>=0.0)? hid : 0.01*hid;
        f64 o2 = wredsum64(hid*(f64)ffn_ow[h]);
        if(h==0) out[gr] = (float)(o2 + (f64)ffn_ob[0]);
      }
    }
  }
}

extern "C" void kernel_launch(void* const* d_in, const int* in_sizes, int n_in,
                              void* d_out, int out_size, void* d_ws, size_t ws_size,
                              hipStream_t stream){
  const float* x      = (const float*)d_in[0];
  const float* fc_in_w= (const float*)d_in[1];
  const float* fc_in_b= (const float*)d_in[2];
  const float* g_in_w = (const float*)d_in[3];
  const float* g_in_b = (const float*)d_in[4];
  const float* g_tr_w = (const float*)d_in[5];
  const float* g_tr_b = (const float*)d_in[6];
  const float* g_a    = (const float*)d_in[7];
  const float* w_ih   = (const float*)d_in[8];
  const float* w_hh   = (const float*)d_in[9];
  const float* b_ih   = (const float*)d_in[10];
  const float* b_hh   = (const float*)d_in[11];
  const float* ffn_w  = (const float*)d_in[12];
  const float* ffn_b  = (const float*)d_in[13];
  const float* ffn_ow = (const float*)d_in[14];
  const float* ffn_ob = (const float*)d_in[15];

  // control region (zeroed every call): 62 iterations x 64 rowgroup counters
  unsigned* cnt = (unsigned*)d_ws;
  hipMemsetAsync(d_ws, 0, NITER*64*sizeof(unsigned), stream);

  f64* fbase = (f64*)((char*)d_ws + 16384);
  f64* h1a   = fbase;
  f64* h1b   = h1a + (long)NROWS*HDIM;
  f64* ssa   = h1b + (long)NROWS*HDIM;
  f64* sda   = ssa + NROWS;
  f64* ssb   = sda + NROWS;
  f64* sdb   = ssb + NROWS;
  f64* w_ihT = sdb + NROWS;
  f64* w_hhT = w_ihT + 192*HDIM;
  f64* pacc  = w_hhT + 192*HDIM;
  f64* pws   = pacc + (long)NCH*NROWS*HDIM;

  float* dout = (float*)d_out;

  k1<<<NROWS/4,256,0,stream>>>(x, fc_in_w, fc_in_b, g_in_w,g_in_b,
                               g_tr_w,g_tr_b,g_a, w_ih,w_hh, w_ihT,w_hhT,
                               h1a,ssa,sda);

  for(int s=0;s<31;s++){
    kAggFin<0><<<512,512,0,stream>>>(h1a,ssa,sda, h1b,ssb,sdb,
                                     pacc,pws, cnt + (2*s)*64,
                                     g_tr_w,g_tr_b,g_a,
                                     x,fc_in_w,fc_in_b,
                                     w_ihT,w_hhT,b_ih,b_hh,
                                     g_in_w,g_in_b,
                                     ffn_w,ffn_b,ffn_ow,ffn_ob,
                                     dout, s, 0);
    kAggFin<1><<<512,512,0,stream>>>(h1b,ssb,sdb, h1a,ssa,sda,
                                     pacc,pws, cnt + (2*s+1)*64,
                                     g_tr_w,g_tr_b,g_a,
                                     x,fc_in_w,fc_in_b,
                                     w_ihT,w_hhT,b_ih,b_hh,
                                     g_in_w,g_in_b,
                                     ffn_w,ffn_b,ffn_ow,ffn_ob,
                                     dout, s, (s==30)?1:0);
  }
}

// Round 11
// 12564.279 us; speedup vs baseline: 1.1629x; 1.1629x over previous
//
#include <hip/hip_runtime.h>
#include <math.h>

typedef double f64;
#define HDIM 64
#define NNODES 1024
#define NROWS 2048
#define RPB 32              // rows per rowgroup / kAggFin block
#define NCH 8               // j-chunks (blocks per rowgroup)
#define CHJ (NNODES/NCH)    // 128 j per chunk
#define NITER 62            // 31 steps x 2 GAT iterations

__device__ __forceinline__ f64 wredsum64(f64 v){
#pragma unroll
  for(int o=32;o>0;o>>=1) v += __shfl_xor(v,o);
  return v;
}

// two-stage score, same op-order as the absmax-0 lineage
__device__ __forceinline__ void s_twostage64(const f64* ldsrow,
    const float* __restrict__ g_tr_w, const float* __restrict__ g_tr_b,
    const float* __restrict__ g_a, int h, f64& s_src, f64& s_dst){
  f64 t = (f64)g_tr_b[h];
  for(int c=0;c<HDIM;c++) t = fma(ldsrow[c], (f64)g_tr_w[c*HDIM+h], t);
  s_src = wredsum64(t*(f64)g_a[h]);
  s_dst = wredsum64(t*(f64)g_a[HDIM+h]);
}

// initial h1 + scores (1 wave/row) + folded f64 weight transpose
__global__ void k1(const float* __restrict__ x, const float* __restrict__ fw,
                   const float* __restrict__ fb,
                   const float* __restrict__ g_in_w, const float* __restrict__ g_in_b,
                   const float* __restrict__ g_tr_w, const float* __restrict__ g_tr_b,
                   const float* __restrict__ g_a,
                   const float* __restrict__ w_ih, const float* __restrict__ w_hh,
                   f64* __restrict__ w_ihT, f64* __restrict__ w_hhT,
                   f64* __restrict__ h1, f64* __restrict__ ssrc, f64* __restrict__ sdst){
  __shared__ f64 lx[4*64];
  __shared__ f64 lt[4*64];
  int wave = threadIdx.x >> 6, h = threadIdx.x & 63;
  int kk = blockIdx.x*256 + threadIdx.x;
  if(kk < 192*HDIM){
    int row=kk>>6, c=kk&63;
    w_ihT[c*192+row]=(f64)w_ih[kk];
    w_hhT[c*192+row]=(f64)w_hh[kk];
  }
  int r = blockIdx.x*4 + wave;
  int b = r >> 10, n = r & 1023;
  const float* xp = x + ((long)(b*32 + 0)*1024 + n)*6;
  f64 xh = (f64)fb[h];
#pragma unroll
  for(int f=0;f<6;f++) xh += (f64)xp[f]*(f64)fw[f*HDIM+h];
  lx[wave*64+h] = xh;
  __syncthreads();
  f64 a = (f64)g_in_b[h];
  for(int c=0;c<HDIM;c++) a += lx[wave*64+c]*(f64)g_in_w[c*HDIM+h];
  h1[(long)r*HDIM+h] = a;
  lt[wave*64+h] = a;
  __syncthreads();
  f64 s1,s2;
  s_twostage64(lt+wave*64, g_tr_w,g_tr_b,g_a, h, s1,s2);
  if(h==0){ ssrc[r]=s1; sdst[r]=s2; }
}

// Fused Agg + last-block Fin. grid = 64 rowgroups x 8 chunks = 512 blocks x 512 thr.
// Phase A (all blocks): partial aggregation for (rowgroup, chunk) -> pacc/pws.
// Phase B (last block of each rowgroup): combine + residual + [scores | GRU+next-h1+scores | FFN].
template<int M>
__global__ __launch_bounds__(512) void kAggFin(
    const f64* __restrict__ h1_in, const f64* __restrict__ ss_in,
    const f64* __restrict__ sd_in,
    f64* __restrict__ h1_out, f64* __restrict__ ss_out, f64* __restrict__ sd_out,
    f64* __restrict__ pacc, f64* __restrict__ pws, unsigned* __restrict__ cnt,
    const float* __restrict__ g_tr_w, const float* __restrict__ g_tr_b,
    const float* __restrict__ g_a,
    const float* __restrict__ x, const float* __restrict__ fw, const float* __restrict__ fb,
    const f64* __restrict__ w_ihT, const f64* __restrict__ w_hhT,
    const float* __restrict__ b_ih, const float* __restrict__ b_hh,
    const float* __restrict__ g_in_w, const float* __restrict__ g_in_b,
    const float* __restrict__ ffn_w, const float* __restrict__ ffn_b,
    const float* __restrict__ ffn_ow, const float* __restrict__ ffn_ob,
    float* __restrict__ out, int step, int is_final)
{
  __shared__ __align__(16) f64 htile[64*64];  // 32 KB (Phase B: lxB/lhB)
  __shared__ __align__(16) f64 wbuf[RPB*64];  // 16 KB (Phase B: lrow)
  __shared__ f64 lds_m[RPB];
  __shared__ f64 lds_sd[RPB];
  __shared__ f64 red[8];
  __shared__ unsigned lastflag;

  const int tid = threadIdx.x, wave = tid>>6, h = tid&63;
  const int chunk = blockIdx.x & (NCH-1);
  const int rg = blockIdx.x >> 3;           // 0..63
  const int batch = rg >> 5;
  const int nloc = (rg & 31)*RPB;           // node base within batch
  const long gr0 = (long)batch*NNODES + nloc;

  // ---- Phase A: identical to R9 kAgg ----
  const f64* sb = ss_in + (long)batch*NNODES;
  f64 mx = -1e300;
  for(int j=tid;j<NNODES;j+=512) mx = fmax(mx, sb[j]);
#pragma unroll
  for(int o=32;o>0;o>>=1) mx = fmax(mx, __shfl_xor(mx,o));
  if(h==0) red[wave]=mx;
  __syncthreads();
  f64 maxS = fmax(fmax(fmax(red[0],red[1]),fmax(red[2],red[3])),
                  fmax(fmax(red[4],red[5]),fmax(red[6],red[7])));
  if(tid<RPB){
    f64 sd = sd_in[gr0+tid];
    lds_sd[tid]=sd;
    f64 v = maxS + sd;
    lds_m[tid] = (v>=0.0)? v : 0.01*v;
  }
  __syncthreads();

  f64 acc0=0.0, acc1=0.0, acc2=0.0, acc3=0.0;
  f64 wsk0=0.0, wsk1=0.0, wsk2=0.0, wsk3=0.0;

  for(int st=0; st<CHJ/64; st++){
    const int j0 = chunk*CHJ + st*64;
    const f64* src = h1_in + ((long)batch*NNODES + j0)*HDIM;
#pragma unroll
    for(int k=0;k<4;k++){
      int idx = tid + k*512;
      ((double2*)htile)[idx] = ((const double2*)src)[idx];
    }
#pragma unroll
    for(int k=0;k<4;k++){
      int idx = tid + k*512;
      int row = idx>>6, jj = idx&63;
      f64 v = sb[j0+jj] + lds_sd[row];
      v = (v>=0.0)? v : 0.01*v;
      f64 e = exp(v - lds_m[row]);
      wbuf[idx] = e;
      if(k==0) wsk0+=e; else if(k==1) wsk1+=e; else if(k==2) wsk2+=e; else wsk3+=e;
    }
    __syncthreads();
    const f64* wb = wbuf + (wave*4)*64;
#pragma unroll 4
    for(int jg=0; jg<16; jg++){
      int base = jg*4*64 + h;
      f64 h0 = htile[base], h1v = htile[base+64];
      f64 h2 = htile[base+128], h3 = htile[base+192];
      double2 wa  = *(const double2*)(wb + jg*4);
      double2 wa2 = *(const double2*)(wb + jg*4 + 2);
      double2 wbv = *(const double2*)(wb + 64 + jg*4);
      double2 wb2 = *(const double2*)(wb + 64 + jg*4 + 2);
      double2 wc  = *(const double2*)(wb + 128 + jg*4);
      double2 wc2 = *(const double2*)(wb + 128 + jg*4 + 2);
      double2 wd  = *(const double2*)(wb + 192 + jg*4);
      double2 wd2 = *(const double2*)(wb + 192 + jg*4 + 2);
      acc0 = fma(wa.x,h0,acc0);  acc0 = fma(wa.y,h1v,acc0);
      acc0 = fma(wa2.x,h2,acc0); acc0 = fma(wa2.y,h3,acc0);
      acc1 = fma(wbv.x,h0,acc1); acc1 = fma(wbv.y,h1v,acc1);
      acc1 = fma(wb2.x,h2,acc1); acc1 = fma(wb2.y,h3,acc1);
      acc2 = fma(wc.x,h0,acc2);  acc2 = fma(wc.y,h1v,acc2);
      acc2 = fma(wc2.x,h2,acc2); acc2 = fma(wc2.y,h3,acc2);
      acc3 = fma(wd.x,h0,acc3);  acc3 = fma(wd.y,h1v,acc3);
      acc3 = fma(wd2.x,h2,acc3); acc3 = fma(wd2.y,h3,acc3);
    }
    __syncthreads();
  }

  const long pbase = (long)chunk*NROWS + gr0;
  pacc[(pbase + wave*4+0)*HDIM + h] = acc0;
  pacc[(pbase + wave*4+1)*HDIM + h] = acc1;
  pacc[(pbase + wave*4+2)*HDIM + h] = acc2;
  pacc[(pbase + wave*4+3)*HDIM + h] = acc3;
  f64 w0 = wredsum64(wsk0), w1 = wredsum64(wsk1);
  f64 w2 = wredsum64(wsk2), w3 = wredsum64(wsk3);
  if(h==0){
    pws[pbase + wave     ] = w0;
    pws[pbase + wave + 8 ] = w1;
    pws[pbase + wave + 16] = w2;
    pws[pbase + wave + 24] = w3;
  }

  // ---- completion protocol: last block of rowgroup does Fin ----
  __syncthreads();                // all stores issued
  if(tid==0){
    __threadfence();              // release
    unsigned old = atomicAdd(&cnt[rg], 1u);
    lastflag = (old == NCH-1);
  }
  __syncthreads();
  if(!lastflag) return;
  __threadfence();                // acquire

  // ---- Phase B: Fin for 32 rows, 8 waves x 4 rows, wave-local ----
  f64* lrow = wbuf;               // [32*64]
  f64* lxB  = htile;              // [32*64]
  f64* lhB  = htile + 2048;       // [32*64]

#pragma unroll
  for(int q=0;q<4;q++){
    int y = wave*4+q; long gr = gr0+y;
    f64 a=0.0, w=0.0;
#pragma unroll
    for(int c=0;c<NCH;c++){
      a += pacc[((long)c*NROWS+gr)*HDIM+h];
      w += pws[(long)c*NROWS+gr];
    }
    f64 gato = a/w + h1_in[gr*HDIM+h];
    lrow[y*64+h]=gato;
    if(M==0) h1_out[gr*HDIM+h] = gato;
  }
  __syncthreads();

  if(M==0){
#pragma unroll
    for(int q=0;q<4;q++){
      int y=wave*4+q; long gr=gr0+y;
      f64 s1,s2; s_twostage64(lrow+y*64, g_tr_w,g_tr_b,g_a,h,s1,s2);
      if(h==0){ ss_out[gr]=s1; sd_out[gr]=s2; }
    }
  } else {
    const bool hasxi = (step>0);
    if(hasxi){
#pragma unroll
      for(int q=0;q<4;q++){
        int y=wave*4+q;
        const float* xp = x + ((long)(batch*32+step)*1024 + nloc+y)*6;
        f64 xi=(f64)fb[h];
#pragma unroll
        for(int f=0;f<6;f++) xi += (f64)xp[f]*(f64)fw[f*HDIM+h];
        lxB[y*64+h]=xi;
      }
    }
    __syncthreads();
#pragma unroll
    for(int q=0;q<4;q++){
      int y=wave*4+q;
      f64 gato = lrow[y*64+h];
      f64 gi0=(f64)b_ih[h], gi1=(f64)b_ih[64+h], gi2=(f64)b_ih[128+h];
      f64 gh0=(f64)b_hh[h], gh1=(f64)b_hh[64+h], gh2=(f64)b_hh[128+h];
      for(int c=0;c<HDIM;c++){
        f64 o = lrow[y*64+c];
        f64 in = hasxi ? lxB[y*64+c] : o;
        gi0 += in*w_ihT[c*192+h]; gi1 += in*w_ihT[c*192+64+h]; gi2 += in*w_ihT[c*192+128+h];
        if(hasxi){
          gh0 += o*w_hhT[c*192+h]; gh1 += o*w_hhT[c*192+64+h]; gh2 += o*w_hhT[c*192+128+h];
        }
      }
      f64 rr = 1.0/(1.0+exp(-(gi0+gh0)));
      f64 zz = 1.0/(1.0+exp(-(gi1+gh1)));
      f64 nn = tanh(gi2 + rr*gh2);
      f64 hn = hasxi ? ((1.0-zz)*nn + zz*gato) : (1.0-zz)*nn;
      lhB[y*64+h] = hn;
    }
    __syncthreads();
    if(!is_final){
#pragma unroll
      for(int q=0;q<4;q++){
        int y=wave*4+q; long gr=gr0+y;
        f64 a1 = (f64)g_in_b[h];
        for(int c=0;c<HDIM;c++) a1 += lhB[y*64+c]*(f64)g_in_w[c*HDIM+h];
        h1_out[gr*HDIM+h]=a1;
        lrow[y*64+h]=a1;
      }
      __syncthreads();
#pragma unroll
      for(int q=0;q<4;q++){
        int y=wave*4+q; long gr=gr0+y;
        f64 s1,s2; s_twostage64(lrow+y*64, g_tr_w,g_tr_b,g_a,h,s1,s2);
        if(h==0){ ss_out[gr]=s1; sd_out[gr]=s2; }
      }
    } else {
#pragma unroll
      for(int q=0;q<4;q++){
        int y=wave*4+q; long gr=gr0+y;
        f64 hid = (f64)ffn_b[h];
        for(int c=0;c<HDIM;c++) hid += lhB[y*64+c]*(f64)ffn_w[c*HDIM+h];
        hid = (hid>=0.0)? hid : 0.01*hid;
        f64 o2 = wredsum64(hid*(f64)ffn_ow[h]);
        if(h==0) out[gr] = (float)(o2 + (f64)ffn_ob[0]);
      }
    }
  }
}

extern "C" void kernel_launch(void* const* d_in, const int* in_sizes, int n_in,
                              void* d_out, int out_size, void* d_ws, size_t ws_size,
                              hipStream_t stream){
  const float* x      = (const float*)d_in[0];
  const float* fc_in_w= (const float*)d_in[1];
  const float* fc_in_b= (const float*)d_in[2];
  const float* g_in_w = (const float*)d_in[3];
  const float* g_in_b = (const float*)d_in[4];
  const float* g_tr_w = (const float*)d_in[5];
  const float* g_tr_b = (const float*)d_in[6];
  const float* g_a    = (const float*)d_in[7];
  const float* w_ih   = (const float*)d_in[8];
  const float* w_hh   = (const float*)d_in[9];
  const float* b_ih   = (const float*)d_in[10];
  const float* b_hh   = (const float*)d_in[11];
  const float* ffn_w  = (const float*)d_in[12];
  const float* ffn_b  = (const float*)d_in[13];
  const float* ffn_ow = (const float*)d_in[14];
  const float* ffn_ob = (const float*)d_in[15];

  // control region (zeroed every call): 62 iterations x 64 rowgroup counters
  unsigned* cnt = (unsigned*)d_ws;
  hipMemsetAsync(d_ws, 0, NITER*64*sizeof(unsigned), stream);

  f64* fbase = (f64*)((char*)d_ws + 16384);
  f64* h1a   = fbase;
  f64* h1b   = h1a + (long)NROWS*HDIM;
  f64* ssa   = h1b + (long)NROWS*HDIM;
  f64* sda   = ssa + NROWS;
  f64* ssb   = sda + NROWS;
  f64* sdb   = ssb + NROWS;
  f64* w_ihT = sdb + NROWS;
  f64* w_hhT = w_ihT + 192*HDIM;
  f64* pacc  = w_hhT + 192*HDIM;
  f64* pws   = pacc + (long)NCH*NROWS*HDIM;

  float* dout = (float*)d_out;

  k1<<<NROWS/4,256,0,stream>>>(x, fc_in_w, fc_in_b, g_in_w,g_in_b,
                               g_tr_w,g_tr_b,g_a, w_ih,w_hh, w_ihT,w_hhT,
                               h1a,ssa,sda);

  for(int s=0;s<31;s++){
    kAggFin<0><<<512,512,0,stream>>>(h1a,ssa,sda, h1b,ssb,sdb,
                                     pacc,pws, cnt + (2*s)*64,
                                     g_tr_w,g_tr_b,g_a,
                                     x,fc_in_w,fc_in_b,
                                     w_ihT,w_hhT,b_ih,b_hh,
                                     g_in_w,g_in_b,
                                     ffn_w,ffn_b,ffn_ow,ffn_ob,
                                     dout, s, 0);
    kAggFin<1><<<512,512,0,stream>>>(h1b,ssb,sdb, h1a,ssa,sda,
                                     pacc,pws, cnt + (2*s+1)*64,
                                     g_tr_w,g_tr_b,g_a,
                                     x,fc_in_w,fc_in_b,
                                     w_ihT,w_hhT,b_ih,b_hh,
                                     g_in_w,g_in_b,
                                     ffn_w,ffn_b,ffn_ow,ffn_ob,
                                     dout, s, (s==30)?1:0);
  }
}

// Round 12
// 4481.243 us; speedup vs baseline: 3.2605x; 2.8037x over previous
//
#include <hip/hip_runtime.h>
#include <math.h>

typedef double f64;
#define HDIM 64
#define NNODES 1024
#define NROWS 2048
#define RPB 16       // rows per block
#define NTHR 512
#define NBLK (NROWS/RPB)   // 128 blocks

__device__ __forceinline__ f64 wredsum64(f64 v){
#pragma unroll
  for(int o=32;o>0;o>>=1) v += __shfl_xor(v,o);
  return v;
}

// two-stage score, same op-order as the absmax-0 lineage
__device__ __forceinline__ void s_twostage64(const f64* ldsrow,
    const float* __restrict__ g_tr_w, const float* __restrict__ g_tr_b,
    const float* __restrict__ g_a, int h, f64& s_src, f64& s_dst){
  f64 t = (f64)g_tr_b[h];
  for(int c=0;c<HDIM;c++) t = fma(ldsrow[c], (f64)g_tr_w[c*HDIM+h], t);
  s_src = wredsum64(t*(f64)g_a[h]);
  s_dst = wredsum64(t*(f64)g_a[HDIM+h]);
}

// initial h1 + scores (1 wave/row) + folded f64 weight transpose  [R9-proven]
__global__ void k1(const float* __restrict__ x, const float* __restrict__ fw,
                   const float* __restrict__ fb,
                   const float* __restrict__ g_in_w, const float* __restrict__ g_in_b,
                   const float* __restrict__ g_tr_w, const float* __restrict__ g_tr_b,
                   const float* __restrict__ g_a,
                   const float* __restrict__ w_ih, const float* __restrict__ w_hh,
                   f64* __restrict__ w_ihT, f64* __restrict__ w_hhT,
                   f64* __restrict__ h1, f64* __restrict__ ssrc, f64* __restrict__ sdst){
  __shared__ f64 lx[4*64];
  __shared__ f64 lt[4*64];
  int wave = threadIdx.x >> 6, h = threadIdx.x & 63;
  int kk = blockIdx.x*256 + threadIdx.x;
  if(kk < 192*HDIM){
    int row=kk>>6, c=kk&63;
    w_ihT[c*192+row]=(f64)w_ih[kk];
    w_hhT[c*192+row]=(f64)w_hh[kk];
  }
  int r = blockIdx.x*4 + wave;
  int b = r >> 10, n = r & 1023;
  const float* xp = x + ((long)(b*32 + 0)*1024 + n)*6;
  f64 xh = (f64)fb[h];
#pragma unroll
  for(int f=0;f<6;f++) xh += (f64)xp[f]*(f64)fw[f*HDIM+h];
  lx[wave*64+h] = xh;
  __syncthreads();
  f64 a = (f64)g_in_b[h];
  for(int c=0;c<HDIM;c++) a += lx[wave*64+c]*(f64)g_in_w[c*HDIM+h];
  h1[(long)r*HDIM+h] = a;
  lt[wave*64+h] = a;
  __syncthreads();
  f64 s1,s2;
  s_twostage64(lt+wave*64, g_tr_w,g_tr_b,g_a, h, s1,s2);
  if(h==0){ ssrc[r]=s1; sdst[r]=s2; }
}

// One full GAT iteration per dispatch. 128 blocks x 512 thr, 16 rows/block,
// full j-range per block (no partials, no combine kernel).
// Inner loop + tails lifted verbatim from the absmax-0 R7 kMain.
// M=0: h1_out = agg + residual, + scores.
// M=1: agg -> gat out; GRU; then next-h1 + scores | FFN head.
template<int M>
__global__ __launch_bounds__(NTHR) void k_att(
    const f64* __restrict__ h1_in, const f64* __restrict__ ss_in,
    const f64* __restrict__ sd_in,
    f64* __restrict__ h1_out, f64* __restrict__ ss_out, f64* __restrict__ sd_out,
    const float* __restrict__ g_tr_w, const float* __restrict__ g_tr_b,
    const float* __restrict__ g_a,
    const float* __restrict__ x, const float* __restrict__ fw, const float* __restrict__ fb,
    const f64* __restrict__ w_ihT, const f64* __restrict__ w_hhT,
    const float* __restrict__ b_ih, const float* __restrict__ b_hh,
    const float* __restrict__ g_in_w, const float* __restrict__ g_in_b,
    const float* __restrict__ ffn_w, const float* __restrict__ ffn_b,
    const float* __restrict__ ffn_ow, const float* __restrict__ ffn_ob,
    float* __restrict__ out, int step, int is_final)
{
  __shared__ __align__(16) f64 htile[64*64];   // 32 KB
  __shared__ __align__(16) f64 wbuf[RPB*64];   // 8 KB
  __shared__ __align__(16) f64 lrow[RPB*64];   // gat-out rows
  __shared__ __align__(16) f64 lx[RPB*64];     // xi rows / next-h1 rows
  __shared__ __align__(16) f64 lh[RPB*64];     // hnew rows
  __shared__ f64 lds_m[RPB], lds_sd[RPB], lds_ws[RPB];
  __shared__ f64 red[8];

  const int tid = threadIdx.x, wave = tid>>6, h = tid&63;
  const int bid = blockIdx.x;
  const int batch = bid>>6;
  const int nloc = (bid&63)*RPB;
  const long gr0 = (long)batch*NNODES + nloc;
  const int yA = wave*2, yB = wave*2+1;
  const long grA = gr0+yA, grB = gr0+yB;

  // batch max of s_src (exact row max via monotonicity)
  const f64* sb = ss_in + (long)batch*NNODES;
  f64 mx = -1e300;
  for(int j=tid;j<NNODES;j+=NTHR) mx = fmax(mx, sb[j]);
#pragma unroll
  for(int o=32;o>0;o>>=1) mx = fmax(mx, __shfl_xor(mx,o));
  if(h==0) red[wave]=mx;
  __syncthreads();
  f64 maxS = fmax(fmax(fmax(red[0],red[1]),fmax(red[2],red[3])),
                  fmax(fmax(red[4],red[5]),fmax(red[6],red[7])));
  if(tid<RPB){
    f64 sd = sd_in[gr0+tid];
    lds_sd[tid]=sd;
    f64 v = maxS + sd;
    lds_m[tid] = (v>=0.0)? v : 0.01*v;
  }
  __syncthreads();

  f64 accA=0.0, accB=0.0;
  f64 wsk0=0.0, wsk1=0.0;   // lane partials: rows wave, 8+wave

  for(int jt=0;jt<16;jt++){
    const int j0 = jt*64;
    const f64* src = h1_in + ((long)batch*NNODES + j0)*HDIM;
#pragma unroll
    for(int k=0;k<4;k++){
      int idx = tid + k*NTHR;  // 2048 double2
      ((double2*)htile)[idx] = ((const double2*)src)[idx];
    }
#pragma unroll
    for(int k=0;k<2;k++){
      int idx = tid + k*NTHR;  // 1024 entries = 16 rows x 64
      int row = idx>>6, jj = idx&63;
      f64 v = sb[j0+jj] + lds_sd[row];
      v = (v>=0.0)? v : 0.01*v;
      f64 e = exp(v - lds_m[row]);
      wbuf[idx] = e;
      if(k==0) wsk0+=e; else wsk1+=e;
    }
    __syncthreads();
    const f64* wb = wbuf + yA*64;
#pragma unroll 4
    for(int jg=0; jg<16; jg++){
      int base = jg*4*64 + h;
      f64 h0 = htile[base], h1v = htile[base+64];
      f64 h2 = htile[base+128], h3 = htile[base+192];
      double2 wa  = *(const double2*)(wb + jg*4);
      double2 wa2 = *(const double2*)(wb + jg*4 + 2);
      double2 wbv = *(const double2*)(wb + 64 + jg*4);
      double2 wb2 = *(const double2*)(wb + 64 + jg*4 + 2);
      accA = fma(wa.x,h0,accA);  accA = fma(wa.y,h1v,accA);
      accA = fma(wa2.x,h2,accA); accA = fma(wa2.y,h3,accA);
      accB = fma(wbv.x,h0,accB); accB = fma(wbv.y,h1v,accB);
      accB = fma(wb2.x,h2,accB); accB = fma(wb2.y,h3,accB);
    }
    __syncthreads();
  }
  f64 w0 = wredsum64(wsk0), w1 = wredsum64(wsk1);
  if(h==0){ lds_ws[wave]=w0; lds_ws[8+wave]=w1; }
  __syncthreads();
  f64 outA = accA/lds_ws[yA] + h1_in[grA*HDIM + h];
  f64 outB = accB/lds_ws[yB] + h1_in[grB*HDIM + h];

  if(M==0){
    h1_out[grA*HDIM+h]=outA; h1_out[grB*HDIM+h]=outB;
    lrow[yA*64+h]=outA; lrow[yB*64+h]=outB;
    __syncthreads();
    f64 sA1,sA2,sB1,sB2;
    s_twostage64(lrow+yA*64, g_tr_w,g_tr_b,g_a, h, sA1,sA2);
    s_twostage64(lrow+yB*64, g_tr_w,g_tr_b,g_a, h, sB1,sB2);
    if(h==0){
      ss_out[grA]=sA1; sd_out[grA]=sA2;
      ss_out[grB]=sB1; sd_out[grB]=sB2;
    }
  } else {
    lrow[yA*64+h]=outA; lrow[yB*64+h]=outB;
    const bool hasxi = (step>0);
    if(hasxi){
      const int nA = nloc+yA, nB = nloc+yB;
      const float* xpA = x + ((long)(batch*32+step)*1024 + nA)*6;
      const float* xpB = x + ((long)(batch*32+step)*1024 + nB)*6;
      f64 xa = (f64)fb[h], xb = (f64)fb[h];
#pragma unroll
      for(int f=0;f<6;f++){
        xa += (f64)xpA[f]*(f64)fw[f*HDIM+h];
        xb += (f64)xpB[f]*(f64)fw[f*HDIM+h];
      }
      lx[yA*64+h]=xa; lx[yB*64+h]=xb;
    }
    __syncthreads();
#pragma unroll
    for(int q=0;q<2;q++){
      const int y = wave*2+q;
      const f64 gato = (q==0)? outA : outB;
      f64 gi0=(f64)b_ih[h], gi1=(f64)b_ih[64+h], gi2=(f64)b_ih[128+h];
      f64 gh0=(f64)b_hh[h], gh1=(f64)b_hh[64+h], gh2=(f64)b_hh[128+h];
      for(int c=0;c<HDIM;c++){
        f64 o = lrow[y*64+c];
        f64 in = hasxi ? lx[y*64+c] : o;
        gi0 += in*w_ihT[c*192+h]; gi1 += in*w_ihT[c*192+64+h]; gi2 += in*w_ihT[c*192+128+h];
        if(hasxi){
          gh0 += o*w_hhT[c*192+h]; gh1 += o*w_hhT[c*192+64+h]; gh2 += o*w_hhT[c*192+128+h];
        }
      }
      f64 rr = 1.0/(1.0+exp(-(gi0+gh0)));
      f64 zz = 1.0/(1.0+exp(-(gi1+gh1)));
      f64 nn = tanh(gi2 + rr*gh2);
      f64 hn = hasxi ? ((1.0-zz)*nn + zz*gato) : (1.0-zz)*nn;
      lh[y*64+h] = hn;
    }
    __syncthreads();
    if(!is_final){
      f64 a1A = (f64)g_in_b[h], a1B = a1A;
      for(int c=0;c<HDIM;c++){
        f64 w = (f64)g_in_w[c*HDIM+h];
        a1A += lh[yA*64+c]*w;
        a1B += lh[yB*64+c]*w;
      }
      h1_out[grA*HDIM+h]=a1A; h1_out[grB*HDIM+h]=a1B;
      lx[yA*64+h]=a1A; lx[yB*64+h]=a1B;
      __syncthreads();
      f64 sA1,sA2,sB1,sB2;
      s_twostage64(lx+yA*64, g_tr_w,g_tr_b,g_a, h, sA1,sA2);
      s_twostage64(lx+yB*64, g_tr_w,g_tr_b,g_a, h, sB1,sB2);
      if(h==0){
        ss_out[grA]=sA1; sd_out[grA]=sA2;
        ss_out[grB]=sB1; sd_out[grB]=sB2;
      }
    } else {
#pragma unroll
      for(int q=0;q<2;q++){
        const int y = wave*2+q;
        const long gr = gr0 + y;
        f64 hid = (f64)ffn_b[h];
        for(int c=0;c<HDIM;c++) hid += lh[y*64+c]*(f64)ffn_w[c*HDIM+h];
        hid = (hid>=0.0)? hid : 0.01*hid;
        f64 o2 = wredsum64(hid*(f64)ffn_ow[h]);
        if(h==0) out[gr] = (float)(o2 + (f64)ffn_ob[0]);
      }
    }
  }
}

extern "C" void kernel_launch(void* const* d_in, const int* in_sizes, int n_in,
                              void* d_out, int out_size, void* d_ws, size_t ws_size,
                              hipStream_t stream){
  const float* x      = (const float*)d_in[0];
  const float* fc_in_w= (const float*)d_in[1];
  const float* fc_in_b= (const float*)d_in[2];
  const float* g_in_w = (const float*)d_in[3];
  const float* g_in_b = (const float*)d_in[4];
  const float* g_tr_w = (const float*)d_in[5];
  const float* g_tr_b = (const float*)d_in[6];
  const float* g_a    = (const float*)d_in[7];
  const float* w_ih   = (const float*)d_in[8];
  const float* w_hh   = (const float*)d_in[9];
  const float* b_ih   = (const float*)d_in[10];
  const float* b_hh   = (const float*)d_in[11];
  const float* ffn_w  = (const float*)d_in[12];
  const float* ffn_b  = (const float*)d_in[13];
  const float* ffn_ow = (const float*)d_in[14];
  const float* ffn_ob = (const float*)d_in[15];

  // workspace (f64): h1 2*131072; scores 4*2048; wT 2*12288 ≈ 2.3 MB
  f64* h1a   = (f64*)d_ws;
  f64* h1b   = h1a + (long)NROWS*HDIM;
  f64* ssa   = h1b + (long)NROWS*HDIM;
  f64* sda   = ssa + NROWS;
  f64* ssb   = sda + NROWS;
  f64* sdb   = ssb + NROWS;
  f64* w_ihT = sdb + NROWS;
  f64* w_hhT = w_ihT + 192*HDIM;

  float* dout = (float*)d_out;

  k1<<<NROWS/4,256,0,stream>>>(x, fc_in_w, fc_in_b, g_in_w,g_in_b,
                               g_tr_w,g_tr_b,g_a, w_ih,w_hh, w_ihT,w_hhT,
                               h1a,ssa,sda);

  for(int s=0;s<31;s++){
    k_att<0><<<NBLK,NTHR,0,stream>>>(h1a,ssa,sda, h1b,ssb,sdb,
                                     g_tr_w,g_tr_b,g_a,
                                     x,fc_in_w,fc_in_b,
                                     w_ihT,w_hhT,b_ih,b_hh,
                                     g_in_w,g_in_b,
                                     ffn_w,ffn_b,ffn_ow,ffn_ob,
                                     dout, s, 0);
    k_att<1><<<NBLK,NTHR,0,stream>>>(h1b,ssb,sdb, h1a,ssa,sda,
                                     g_tr_w,g_tr_b,g_a,
                                     x,fc_in_w,fc_in_b,
                                     w_ihT,w_hhT,b_ih,b_hh,
                                     g_in_w,g_in_b,
                                     ffn_w,ffn_b,ffn_ow,ffn_ob,
                                     dout, s, (s==30)?1:0);
  }
}

// Round 13
// 4428.347 us; speedup vs baseline: 3.2994x; 1.0119x over previous
//
#include <hip/hip_runtime.h>
#include <math.h>

typedef double f64;
#define HDIM 64
#define NNODES 1024
#define NROWS 2048
#define RPB 8              // rows per block
#define NTHR 256
#define NBLK (NROWS/RPB)   // 256 blocks

__device__ __forceinline__ f64 wredsum64(f64 v){
#pragma unroll
  for(int o=32;o>0;o>>=1) v += __shfl_xor(v,o);
  return v;
}

// two-stage score, same op-order as the absmax-0 lineage
__device__ __forceinline__ void s_twostage64(const f64* ldsrow,
    const float* __restrict__ g_tr_w, const float* __restrict__ g_tr_b,
    const float* __restrict__ g_a, int h, f64& s_src, f64& s_dst){
  f64 t = (f64)g_tr_b[h];
  for(int c=0;c<HDIM;c++) t = fma(ldsrow[c], (f64)g_tr_w[c*HDIM+h], t);
  s_src = wredsum64(t*(f64)g_a[h]);
  s_dst = wredsum64(t*(f64)g_a[HDIM+h]);
}

// initial h1 + scores (1 wave/row) + folded f64 weight transpose
__global__ void k1(const float* __restrict__ x, const float* __restrict__ fw,
                   const float* __restrict__ fb,
                   const float* __restrict__ g_in_w, const float* __restrict__ g_in_b,
                   const float* __restrict__ g_tr_w, const float* __restrict__ g_tr_b,
                   const float* __restrict__ g_a,
                   const float* __restrict__ w_ih, const float* __restrict__ w_hh,
                   f64* __restrict__ w_ihT, f64* __restrict__ w_hhT,
                   f64* __restrict__ h1, f64* __restrict__ ssrc, f64* __restrict__ sdst){
  __shared__ f64 lx[4*64];
  __shared__ f64 lt[4*64];
  int wave = threadIdx.x >> 6, h = threadIdx.x & 63;
  int kk = blockIdx.x*256 + threadIdx.x;
  if(kk < 192*HDIM){
    int row=kk>>6, c=kk&63;
    w_ihT[c*192+row]=(f64)w_ih[kk];
    w_hhT[c*192+row]=(f64)w_hh[kk];
  }
  int r = blockIdx.x*4 + wave;
  int b = r >> 10, n = r & 1023;
  const float* xp = x + ((long)(b*32 + 0)*1024 + n)*6;
  f64 xh = (f64)fb[h];
#pragma unroll
  for(int f=0;f<6;f++) xh += (f64)xp[f]*(f64)fw[f*HDIM+h];
  lx[wave*64+h] = xh;
  __syncthreads();
  f64 a = (f64)g_in_b[h];
  for(int c=0;c<HDIM;c++) a += lx[wave*64+c]*(f64)g_in_w[c*HDIM+h];
  h1[(long)r*HDIM+h] = a;
  lt[wave*64+h] = a;
  __syncthreads();
  f64 s1,s2;
  s_twostage64(lt+wave*64, g_tr_w,g_tr_b,g_a, h, s1,s2);
  if(h==0){ ssrc[r]=s1; sdst[r]=s2; }
}

// One full GAT iteration per dispatch. 256 blocks x 256 thr, 8 rows/block,
// full j-range per block, per-block tile ROTATION (L2 de-hotspot) +
// register PREFETCH of the next tile (latency hiding under FMA).
// M=0: h1_out = agg + residual, + scores.
// M=1: agg -> gat out; GRU; then next-h1 + scores | FFN head.
template<int M>
__global__ __launch_bounds__(NTHR) void k_att(
    const f64* __restrict__ h1_in, const f64* __restrict__ ss_in,
    const f64* __restrict__ sd_in,
    f64* __restrict__ h1_out, f64* __restrict__ ss_out, f64* __restrict__ sd_out,
    const float* __restrict__ g_tr_w, const float* __restrict__ g_tr_b,
    const float* __restrict__ g_a,
    const float* __restrict__ x, const float* __restrict__ fw, const float* __restrict__ fb,
    const f64* __restrict__ w_ihT, const f64* __restrict__ w_hhT,
    const float* __restrict__ b_ih, const float* __restrict__ b_hh,
    const float* __restrict__ g_in_w, const float* __restrict__ g_in_b,
    const float* __restrict__ ffn_w, const float* __restrict__ ffn_b,
    const float* __restrict__ ffn_ow, const float* __restrict__ ffn_ob,
    float* __restrict__ out, int step, int is_final)
{
  __shared__ __align__(16) f64 htile[64*64];   // 32 KB
  __shared__ __align__(16) f64 wbuf[RPB*64];   // 4 KB
  __shared__ __align__(16) f64 lrow[RPB*64];
  __shared__ __align__(16) f64 lx[RPB*64];
  __shared__ __align__(16) f64 lh[RPB*64];
  __shared__ f64 lds_m[RPB], lds_sd[RPB], lds_ws[RPB];
  __shared__ f64 red[4];

  const int tid = threadIdx.x, wave = tid>>6, h = tid&63;
  const int bid = blockIdx.x;
  const int batch = bid>>7;
  const int nloc = (bid&127)*RPB;
  const long gr0 = (long)batch*NNODES + nloc;
  const int yA = wave*2, yB = wave*2+1;
  const long grA = gr0+yA, grB = gr0+yB;

  // batch max of s_src (exact row max via monotonicity; max is order-exact)
  const f64* sb = ss_in + (long)batch*NNODES;
  f64 mx = -1e300;
  for(int j=tid;j<NNODES;j+=NTHR) mx = fmax(mx, sb[j]);
#pragma unroll
  for(int o=32;o>0;o>>=1) mx = fmax(mx, __shfl_xor(mx,o));
  if(h==0) red[wave]=mx;
  __syncthreads();
  f64 maxS = fmax(fmax(red[0],red[1]),fmax(red[2],red[3]));
  if(tid<RPB){
    f64 sd = sd_in[gr0+tid];
    lds_sd[tid]=sd;
    f64 v = maxS + sd;
    lds_m[tid] = (v>=0.0)? v : 0.01*v;
  }

  f64 accA=0.0, accB=0.0;
  f64 wsk0=0.0, wsk1=0.0;   // lane partials: rows wave, 4+wave

  const f64* hbase = h1_in + (long)batch*NNODES*HDIM;
  const int t0 = bid & 15;   // tile rotation

  // prologue: prefetch first tile into registers
  double2 r[8];
  {
    const double2* srcv = (const double2*)(hbase + (long)(t0*64)*HDIM);
#pragma unroll
    for(int k=0;k<8;k++) r[k] = srcv[tid + k*NTHR];
  }
  __syncthreads();   // lds_m/lds_sd ready

  for(int tt=0;tt<16;tt++){
    const int jt = (t0 + tt) & 15;
    const int j0 = jt*64;
    // write prefetched tile to LDS
#pragma unroll
    for(int k=0;k<8;k++) ((double2*)htile)[tid + k*NTHR] = r[k];
    // softmax weights for this tile (exact op order)
#pragma unroll
    for(int k=0;k<2;k++){
      int idx = tid + k*NTHR;  // 512 entries = 8 rows x 64
      int row = idx>>6, jj = idx&63;
      f64 v = sb[j0+jj] + lds_sd[row];
      v = (v>=0.0)? v : 0.01*v;
      f64 e = exp(v - lds_m[row]);
      wbuf[idx] = e;
      if(k==0) wsk0+=e; else wsk1+=e;
    }
    __syncthreads();
    // issue prefetch for next tile (completes under the FMA loop)
    if(tt<15){
      const int jn = (t0 + tt + 1) & 15;
      const double2* srcv = (const double2*)(hbase + (long)(jn*64)*HDIM);
#pragma unroll
      for(int k=0;k<8;k++) r[k] = srcv[tid + k*NTHR];
    }
    // FMA over current tile
    const f64* wb = wbuf + yA*64;
#pragma unroll 4
    for(int jg=0; jg<16; jg++){
      int base = jg*4*64 + h;
      f64 h0 = htile[base], h1v = htile[base+64];
      f64 h2 = htile[base+128], h3 = htile[base+192];
      double2 wa  = *(const double2*)(wb + jg*4);
      double2 wa2 = *(const double2*)(wb + jg*4 + 2);
      double2 wbv = *(const double2*)(wb + 64 + jg*4);
      double2 wb2 = *(const double2*)(wb + 64 + jg*4 + 2);
      accA = fma(wa.x,h0,accA);  accA = fma(wa.y,h1v,accA);
      accA = fma(wa2.x,h2,accA); accA = fma(wa2.y,h3,accA);
      accB = fma(wbv.x,h0,accB); accB = fma(wbv.y,h1v,accB);
      accB = fma(wb2.x,h2,accB); accB = fma(wb2.y,h3,accB);
    }
    __syncthreads();
  }
  f64 w0 = wredsum64(wsk0), w1 = wredsum64(wsk1);
  if(h==0){ lds_ws[wave]=w0; lds_ws[4+wave]=w1; }
  __syncthreads();
  f64 outA = accA/lds_ws[yA] + h1_in[grA*HDIM + h];
  f64 outB = accB/lds_ws[yB] + h1_in[grB*HDIM + h];

  if(M==0){
    h1_out[grA*HDIM+h]=outA; h1_out[grB*HDIM+h]=outB;
    lrow[yA*64+h]=outA; lrow[yB*64+h]=outB;
    __syncthreads();
    f64 sA1,sA2,sB1,sB2;
    s_twostage64(lrow+yA*64, g_tr_w,g_tr_b,g_a, h, sA1,sA2);
    s_twostage64(lrow+yB*64, g_tr_w,g_tr_b,g_a, h, sB1,sB2);
    if(h==0){
      ss_out[grA]=sA1; sd_out[grA]=sA2;
      ss_out[grB]=sB1; sd_out[grB]=sB2;
    }
  } else {
    lrow[yA*64+h]=outA; lrow[yB*64+h]=outB;
    const bool hasxi = (step>0);
    if(hasxi){
      const int nA = nloc+yA, nB = nloc+yB;
      const float* xpA = x + ((long)(batch*32+step)*1024 + nA)*6;
      const float* xpB = x + ((long)(batch*32+step)*1024 + nB)*6;
      f64 xa = (f64)fb[h], xb = (f64)fb[h];
#pragma unroll
      for(int f=0;f<6;f++){
        xa += (f64)xpA[f]*(f64)fw[f*HDIM+h];
        xb += (f64)xpB[f]*(f64)fw[f*HDIM+h];
      }
      lx[yA*64+h]=xa; lx[yB*64+h]=xb;
    }
    __syncthreads();
#pragma unroll
    for(int q=0;q<2;q++){
      const int y = wave*2+q;
      const f64 gato = (q==0)? outA : outB;
      f64 gi0=(f64)b_ih[h], gi1=(f64)b_ih[64+h], gi2=(f64)b_ih[128+h];
      f64 gh0=(f64)b_hh[h], gh1=(f64)b_hh[64+h], gh2=(f64)b_hh[128+h];
      for(int c=0;c<HDIM;c++){
        f64 o = lrow[y*64+c];
        f64 in = hasxi ? lx[y*64+c] : o;
        gi0 += in*w_ihT[c*192+h]; gi1 += in*w_ihT[c*192+64+h]; gi2 += in*w_ihT[c*192+128+h];
        if(hasxi){
          gh0 += o*w_hhT[c*192+h]; gh1 += o*w_hhT[c*192+64+h]; gh2 += o*w_hhT[c*192+128+h];
        }
      }
      f64 rr = 1.0/(1.0+exp(-(gi0+gh0)));
      f64 zz = 1.0/(1.0+exp(-(gi1+gh1)));
      f64 nn = tanh(gi2 + rr*gh2);
      f64 hn = hasxi ? ((1.0-zz)*nn + zz*gato) : (1.0-zz)*nn;
      lh[y*64+h] = hn;
    }
    __syncthreads();
    if(!is_final){
      f64 a1A = (f64)g_in_b[h], a1B = a1A;
      for(int c=0;c<HDIM;c++){
        f64 w = (f64)g_in_w[c*HDIM+h];
        a1A += lh[yA*64+c]*w;
        a1B += lh[yB*64+c]*w;
      }
      h1_out[grA*HDIM+h]=a1A; h1_out[grB*HDIM+h]=a1B;
      lx[yA*64+h]=a1A; lx[yB*64+h]=a1B;
      __syncthreads();
      f64 sA1,sA2,sB1,sB2;
      s_twostage64(lx+yA*64, g_tr_w,g_tr_b,g_a, h, sA1,sA2);
      s_twostage64(lx+yB*64, g_tr_w,g_tr_b,g_a, h, sB1,sB2);
      if(h==0){
        ss_out[grA]=sA1; sd_out[grA]=sA2;
        ss_out[grB]=sB1; sd_out[grB]=sB2;
      }
    } else {
#pragma unroll
      for(int q=0;q<2;q++){
        const int y = wave*2+q;
        const long gr = gr0 + y;
        f64 hid = (f64)ffn_b[h];
        for(int c=0;c<HDIM;c++) hid += lh[y*64+c]*(f64)ffn_w[c*HDIM+h];
        hid = (hid>=0.0)? hid : 0.01*hid;
        f64 o2 = wredsum64(hid*(f64)ffn_ow[h]);
        if(h==0) out[gr] = (float)(o2 + (f64)ffn_ob[0]);
      }
    }
  }
}

extern "C" void kernel_launch(void* const* d_in, const int* in_sizes, int n_in,
                              void* d_out, int out_size, void* d_ws, size_t ws_size,
                              hipStream_t stream){
  const float* x      = (const float*)d_in[0];
  const float* fc_in_w= (const float*)d_in[1];
  const float* fc_in_b= (const float*)d_in[2];
  const float* g_in_w = (const float*)d_in[3];
  const float* g_in_b = (const float*)d_in[4];
  const float* g_tr_w = (const float*)d_in[5];
  const float* g_tr_b = (const float*)d_in[6];
  const float* g_a    = (const float*)d_in[7];
  const float* w_ih   = (const float*)d_in[8];
  const float* w_hh   = (const float*)d_in[9];
  const float* b_ih   = (const float*)d_in[10];
  const float* b_hh   = (const float*)d_in[11];
  const float* ffn_w  = (const float*)d_in[12];
  const float* ffn_b  = (const float*)d_in[13];
  const float* ffn_ow = (const float*)d_in[14];
  const float* ffn_ob = (const float*)d_in[15];

  f64* h1a   = (f64*)d_ws;
  f64* h1b   = h1a + (long)NROWS*HDIM;
  f64* ssa   = h1b + (long)NROWS*HDIM;
  f64* sda   = ssa + NROWS;
  f64* ssb   = sda + NROWS;
  f64* sdb   = ssb + NROWS;
  f64* w_ihT = sdb + NROWS;
  f64* w_hhT = w_ihT + 192*HDIM;

  float* dout = (float*)d_out;

  k1<<<NROWS/4,256,0,stream>>>(x, fc_in_w, fc_in_b, g_in_w,g_in_b,
                               g_tr_w,g_tr_b,g_a, w_ih,w_hh, w_ihT,w_hhT,
                               h1a,ssa,sda);

  for(int s=0;s<31;s++){
    k_att<0><<<NBLK,NTHR,0,stream>>>(h1a,ssa,sda, h1b,ssb,sdb,
                                     g_tr_w,g_tr_b,g_a,
                                     x,fc_in_w,fc_in_b,
                                     w_ihT,w_hhT,b_ih,b_hh,
                                     g_in_w,g_in_b,
                                     ffn_w,ffn_b,ffn_ow,ffn_ob,
                                     dout, s, 0);
    k_att<1><<<NBLK,NTHR,0,stream>>>(h1b,ssb,sdb, h1a,ssa,sda,
                                     g_tr_w,g_tr_b,g_a,
                                     x,fc_in_w,fc_in_b,
                                     w_ihT,w_hhT,b_ih,b_hh,
                                     g_in_w,g_in_b,
                                     ffn_w,ffn_b,ffn_ow,ffn_ob,
                                     dout, s, (s==30)?1:0);
  }
}

// Round 14
// 3115.144 us; speedup vs baseline: 4.6903x; 1.4216x over previous
//
#include <hip/hip_runtime.h>
#include <math.h>

typedef double f64;
#define HDIM 64
#define NNODES 1024
#define NROWS 2048
#define RPB 4              // rows per block (1 per wave)
#define NTHR 256
#define NBLK (NROWS/RPB)   // 512 blocks -> 2 blocks/CU
#define HTILE_J 64

__device__ __forceinline__ f64 wredsum64(f64 v){
#pragma unroll
  for(int o=32;o>0;o>>=1) v += __shfl_xor(v,o);
  return v;
}

// two-stage score, same op-order as the absmax-0 lineage
__device__ __forceinline__ void s_twostage64(const f64* ldsrow,
    const float* __restrict__ g_tr_w, const float* __restrict__ g_tr_b,
    const float* __restrict__ g_a, int h, f64& s_src, f64& s_dst){
  f64 t = (f64)g_tr_b[h];
  for(int c=0;c<HDIM;c++) t = fma(ldsrow[c], (f64)g_tr_w[c*HDIM+h], t);
  s_src = wredsum64(t*(f64)g_a[h]);
  s_dst = wredsum64(t*(f64)g_a[HDIM+h]);
}

// initial h1 + scores (1 wave/row) + folded f64 weight transpose
__global__ void k1(const float* __restrict__ x, const float* __restrict__ fw,
                   const float* __restrict__ fb,
                   const float* __restrict__ g_in_w, const float* __restrict__ g_in_b,
                   const float* __restrict__ g_tr_w, const float* __restrict__ g_tr_b,
                   const float* __restrict__ g_a,
                   const float* __restrict__ w_ih, const float* __restrict__ w_hh,
                   f64* __restrict__ w_ihT, f64* __restrict__ w_hhT,
                   f64* __restrict__ h1, f64* __restrict__ ssrc, f64* __restrict__ sdst){
  __shared__ f64 lx[4*64];
  __shared__ f64 lt[4*64];
  int wave = threadIdx.x >> 6, h = threadIdx.x & 63;
  int kk = blockIdx.x*256 + threadIdx.x;
  if(kk < 192*HDIM){
    int row=kk>>6, c=kk&63;
    w_ihT[c*192+row]=(f64)w_ih[kk];
    w_hhT[c*192+row]=(f64)w_hh[kk];
  }
  int r = blockIdx.x*4 + wave;
  int b = r >> 10, n = r & 1023;
  const float* xp = x + ((long)(b*32 + 0)*1024 + n)*6;
  f64 xh = (f64)fb[h];
#pragma unroll
  for(int f=0;f<6;f++) xh += (f64)xp[f]*(f64)fw[f*HDIM+h];
  lx[wave*64+h] = xh;
  __syncthreads();
  f64 a = (f64)g_in_b[h];
  for(int c=0;c<HDIM;c++) a += lx[wave*64+c]*(f64)g_in_w[c*HDIM+h];
  h1[(long)r*HDIM+h] = a;
  lt[wave*64+h] = a;
  __syncthreads();
  f64 s1,s2;
  s_twostage64(lt+wave*64, g_tr_w,g_tr_b,g_a, h, s1,s2);
  if(h==0){ ssrc[r]=s1; sdst[r]=s2; }
}

// One full GAT iteration per dispatch. 512 blocks x 256 thr, 4 rows/block
// (1 row/wave), full j-range per block with per-block tile rotation.
// 2 blocks/CU co-resident -> staging of one block overlaps FMA of the other.
// M=0: h1_out = agg + residual, + scores.
// M=1: agg -> gat out; GRU; then next-h1 + scores | FFN head.
template<int M>
__global__ __launch_bounds__(NTHR) void k_att(
    const f64* __restrict__ h1_in, const f64* __restrict__ ss_in,
    const f64* __restrict__ sd_in,
    f64* __restrict__ h1_out, f64* __restrict__ ss_out, f64* __restrict__ sd_out,
    const float* __restrict__ g_tr_w, const float* __restrict__ g_tr_b,
    const float* __restrict__ g_a,
    const float* __restrict__ x, const float* __restrict__ fw, const float* __restrict__ fb,
    const f64* __restrict__ w_ihT, const f64* __restrict__ w_hhT,
    const float* __restrict__ b_ih, const float* __restrict__ b_hh,
    const float* __restrict__ g_in_w, const float* __restrict__ g_in_b,
    const float* __restrict__ ffn_w, const float* __restrict__ ffn_b,
    const float* __restrict__ ffn_ow, const float* __restrict__ ffn_ob,
    float* __restrict__ out, int step, int is_final)
{
  __shared__ __align__(16) f64 htile[HTILE_J*64];  // 32 KB
  __shared__ __align__(16) f64 wbuf[RPB*64];       // 2 KB
  __shared__ __align__(16) f64 lrow[RPB*64];
  __shared__ __align__(16) f64 lx[RPB*64];
  __shared__ __align__(16) f64 lh[RPB*64];
  __shared__ f64 lds_m[RPB], lds_sd[RPB], lds_ws[RPB];
  __shared__ f64 red[4];

  const int tid = threadIdx.x, wave = tid>>6, h = tid&63;
  const int bid = blockIdx.x;
  const int batch = bid>>8;              // 256 blocks per batch
  const int nloc = (bid&255)*RPB;
  const long gr0 = (long)batch*NNODES + nloc;
  const int y = wave;                    // this wave's row (0..3)
  const long gry = gr0 + y;

  // batch max of s_src (exact row max via monotonicity; max is order-exact)
  const f64* sb = ss_in + (long)batch*NNODES;
  f64 mx = -1e300;
  for(int j=tid;j<NNODES;j+=NTHR) mx = fmax(mx, sb[j]);
#pragma unroll
  for(int o=32;o>0;o>>=1) mx = fmax(mx, __shfl_xor(mx,o));
  if(h==0) red[wave]=mx;
  __syncthreads();
  f64 maxS = fmax(fmax(red[0],red[1]),fmax(red[2],red[3]));
  if(tid<RPB){
    f64 sd = sd_in[gr0+tid];
    lds_sd[tid]=sd;
    f64 v = maxS + sd;
    lds_m[tid] = (v>=0.0)? v : 0.01*v;
  }
  __syncthreads();

  f64 acc=0.0;      // this wave's row aggregation
  f64 wsk=0.0;      // lane-partial ws for this wave's row

  const f64* hbase = h1_in + (long)batch*NNODES*HDIM;
  const int t0 = bid & 15;   // tile rotation (L2 de-hotspot)

  for(int tt=0;tt<16;tt++){
    const int jt = (t0 + tt) & 15;
    const int j0 = jt*64;
    // stage tile: 2048 double2, 8 per thread (plain load->LDS; cross-block overlap)
    const double2* srcv = (const double2*)(hbase + (long)j0*HDIM);
#pragma unroll
    for(int k=0;k<8;k++){
      int idx = tid + k*NTHR;
      ((double2*)htile)[idx] = srcv[idx];
    }
    // softmax weights: 256 entries = 4 rows x 64; thread tid -> row=wave, lane jj
    {
      int row = wave, jj = h;
      f64 v = sb[j0+jj] + lds_sd[row];
      v = (v>=0.0)? v : 0.01*v;
      f64 e = exp(v - lds_m[row]);
      wbuf[tid] = e;
      wsk += e;
    }
    __syncthreads();
    const f64* wb = wbuf + y*64;
#pragma unroll 4
    for(int jg=0; jg<16; jg++){
      int base = jg*4*64 + h;
      f64 h0 = htile[base], h1v = htile[base+64];
      f64 h2 = htile[base+128], h3 = htile[base+192];
      double2 wa  = *(const double2*)(wb + jg*4);
      double2 wa2 = *(const double2*)(wb + jg*4 + 2);
      acc = fma(wa.x,h0,acc);  acc = fma(wa.y,h1v,acc);
      acc = fma(wa2.x,h2,acc); acc = fma(wa2.y,h3,acc);
    }
    __syncthreads();
  }
  f64 w0 = wredsum64(wsk);
  if(h==0) lds_ws[wave]=w0;
  __syncthreads();
  f64 outv = acc/lds_ws[y] + h1_in[gry*HDIM + h];

  if(M==0){
    h1_out[gry*HDIM+h]=outv;
    lrow[y*64+h]=outv;
    __syncthreads();
    f64 s1,s2;
    s_twostage64(lrow+y*64, g_tr_w,g_tr_b,g_a, h, s1,s2);
    if(h==0){ ss_out[gry]=s1; sd_out[gry]=s2; }
  } else {
    lrow[y*64+h]=outv;
    const bool hasxi = (step>0);
    if(hasxi){
      const float* xp = x + ((long)(batch*32+step)*1024 + nloc+y)*6;
      f64 xa = (f64)fb[h];
#pragma unroll
      for(int f=0;f<6;f++) xa += (f64)xp[f]*(f64)fw[f*HDIM+h];
      lx[y*64+h]=xa;
    }
    __syncthreads();
    // GRU (same c-order as absmax-0 lineage)
    {
      f64 gi0=(f64)b_ih[h], gi1=(f64)b_ih[64+h], gi2=(f64)b_ih[128+h];
      f64 gh0=(f64)b_hh[h], gh1=(f64)b_hh[64+h], gh2=(f64)b_hh[128+h];
      for(int c=0;c<HDIM;c++){
        f64 o = lrow[y*64+c];
        f64 in = hasxi ? lx[y*64+c] : o;
        gi0 += in*w_ihT[c*192+h]; gi1 += in*w_ihT[c*192+64+h]; gi2 += in*w_ihT[c*192+128+h];
        if(hasxi){
          gh0 += o*w_hhT[c*192+h]; gh1 += o*w_hhT[c*192+64+h]; gh2 += o*w_hhT[c*192+128+h];
        }
      }
      f64 rr = 1.0/(1.0+exp(-(gi0+gh0)));
      f64 zz = 1.0/(1.0+exp(-(gi1+gh1)));
      f64 nn = tanh(gi2 + rr*gh2);
      f64 hn = hasxi ? ((1.0-zz)*nn + zz*outv) : (1.0-zz)*nn;
      lh[y*64+h] = hn;
    }
    __syncthreads();
    if(!is_final){
      f64 a1 = (f64)g_in_b[h];
      for(int c=0;c<HDIM;c++) a1 += lh[y*64+c]*(f64)g_in_w[c*HDIM+h];
      h1_out[gry*HDIM+h]=a1;
      lx[y*64+h]=a1;
      __syncthreads();
      f64 s1,s2;
      s_twostage64(lx+y*64, g_tr_w,g_tr_b,g_a, h, s1,s2);
      if(h==0){ ss_out[gry]=s1; sd_out[gry]=s2; }
    } else {
      f64 hid = (f64)ffn_b[h];
      for(int c=0;c<HDIM;c++) hid += lh[y*64+c]*(f64)ffn_w[c*HDIM+h];
      hid = (hid>=0.0)? hid : 0.01*hid;
      f64 o2 = wredsum64(hid*(f64)ffn_ow[h]);
      if(h==0) out[gry] = (float)(o2 + (f64)ffn_ob[0]);
    }
  }
}

extern "C" void kernel_launch(void* const* d_in, const int* in_sizes, int n_in,
                              void* d_out, int out_size, void* d_ws, size_t ws_size,
                              hipStream_t stream){
  const float* x      = (const float*)d_in[0];
  const float* fc_in_w= (const float*)d_in[1];
  const float* fc_in_b= (const float*)d_in[2];
  const float* g_in_w = (const float*)d_in[3];
  const float* g_in_b = (const float*)d_in[4];
  const float* g_tr_w = (const float*)d_in[5];
  const float* g_tr_b = (const float*)d_in[6];
  const float* g_a    = (const float*)d_in[7];
  const float* w_ih   = (const float*)d_in[8];
  const float* w_hh   = (const float*)d_in[9];
  const float* b_ih   = (const float*)d_in[10];
  const float* b_hh   = (const float*)d_in[11];
  const float* ffn_w  = (const float*)d_in[12];
  const float* ffn_b  = (const float*)d_in[13];
  const float* ffn_ow = (const float*)d_in[14];
  const float* ffn_ob = (const float*)d_in[15];

  f64* h1a   = (f64*)d_ws;
  f64* h1b   = h1a + (long)NROWS*HDIM;
  f64* ssa   = h1b + (long)NROWS*HDIM;
  f64* sda   = ssa + NROWS;
  f64* ssb   = sda + NROWS;
  f64* sdb   = ssb + NROWS;
  f64* w_ihT = sdb + NROWS;
  f64* w_hhT = w_ihT + 192*HDIM;

  float* dout = (float*)d_out;

  k1<<<NROWS/4,256,0,stream>>>(x, fc_in_w, fc_in_b, g_in_w,g_in_b,
                               g_tr_w,g_tr_b,g_a, w_ih,w_hh, w_ihT,w_hhT,
                               h1a,ssa,sda);

  for(int s=0;s<31;s++){
    k_att<0><<<NBLK,NTHR,0,stream>>>(h1a,ssa,sda, h1b,ssb,sdb,
                                     g_tr_w,g_tr_b,g_a,
                                     x,fc_in_w,fc_in_b,
                                     w_ihT,w_hhT,b_ih,b_hh,
                                     g_in_w,g_in_b,
                                     ffn_w,ffn_b,ffn_ow,ffn_ob,
                                     dout, s, 0);
    k_att<1><<<NBLK,NTHR,0,stream>>>(h1b,ssb,sdb, h1a,ssa,sda,
                                     g_tr_w,g_tr_b,g_a,
                                     x,fc_in_w,fc_in_b,
                                     w_ihT,w_hhT,b_ih,b_hh,
                                     g_in_w,g_in_b,
                                     ffn_w,ffn_b,ffn_ow,ffn_ob,
                                     dout, s, (s==30)?1:0);
  }
}